// Round 2
// baseline (81.980 us; speedup 1.0000x reference)
//
#include <hip/hip_runtime.h>
#include <hip/hip_bf16.h>

// GaussianBasis: 2D gaussian splatting, N=10000 gaussians -> (3,256,256) fp32 image.
// All inputs/outputs are float32 (per reference). Scatter formulation: each
// gaussian's visible footprint (alpha >= 1/255) is a small ellipse
// (cov_xx <= 2.25, cov_yy <= 3.25 => bbox ~ 11x13 px), so we splat with fp32
// atomics into d_ws and apply scale/shift at the end.

#define IMG_H 256
#define IMG_W 256

__global__ __launch_bounds__(64) void splat_kernel(
    const float* __restrict__ xyz,      // (N,2)
    const float* __restrict__ chol,     // (N,3)
    const float* __restrict__ colors,   // (N,3)
    const float* __restrict__ opacity,  // (N,1)
    float* __restrict__ acc)            // (3,H,W) fp32
{
    const int n = blockIdx.x;

    // Per-gaussian parameters, computed redundantly by all 64 lanes (cheap).
    const float mx = tanhf(xyz[2 * n + 0]);
    const float my = tanhf(xyz[2 * n + 1]);
    const float cx = 0.5f * IMG_W * (mx + 1.0f);
    const float cy = 0.5f * IMG_H * (my + 1.0f);

    const float L0 = chol[3 * n + 0] + 0.5f;
    const float L1 = chol[3 * n + 1] + 0.0f;
    const float L2 = chol[3 * n + 2] + 0.5f;
    const float cov_xx = L0 * L0;
    const float cov_xy = L0 * L1;
    const float cov_yy = L1 * L1 + L2 * L2;
    const float det = cov_xx * cov_yy - cov_xy * cov_xy;

    const float conic_a = cov_yy / det;
    const float conic_b = -cov_xy / det;
    const float conic_c = cov_xx / det;

    const float op = opacity[n];

    // alpha = op * exp(-sigma) >= 1/255  =>  sigma <= ln(255*op) = smax
    const float smax = logf(255.0f * op);
    if (!(smax > 0.0f)) return;  // never visible (or op <= 1/255)

    // Ellipse {sigma == smax}: max |dx| = sqrt(2*smax*cov_xx), max |dy| =
    // sqrt(2*smax*cov_yy). +1 px safety margin; the exact per-pixel mask
    // below decides inclusion, so the margin only costs a few evals.
    const float rx = sqrtf(2.0f * smax * cov_xx) + 1.0f;
    const float ry = sqrtf(2.0f * smax * cov_yy) + 1.0f;
    const int x0 = max(0, (int)floorf(cx - rx));
    const int x1 = min(IMG_W - 1, (int)ceilf(cx + rx));
    const int y0 = max(0, (int)floorf(cy - ry));
    const int y1 = min(IMG_H - 1, (int)ceilf(cy + ry));
    if (x0 > x1 || y0 > y1) return;

    const int bw = x1 - x0 + 1;
    const int npix = bw * (y1 - y0 + 1);

    const float c0 = colors[3 * n + 0];
    const float c1 = colors[3 * n + 1];
    const float c2 = colors[3 * n + 2];

    for (int i = threadIdx.x; i < npix; i += 64) {
        const int yy = i / bw;
        const int xx = i - yy * bw;
        const float dx = cx - (float)(x0 + xx);
        const float dy = cy - (float)(y0 + yy);
        const float sigma =
            0.5f * (conic_a * dx * dx + conic_c * dy * dy) + conic_b * (dx * dy);
        float alpha = op * expf(-sigma);
        if (sigma >= 0.0f && alpha >= (1.0f / 255.0f)) {
            alpha = fminf(alpha, 0.999f);
            const int pix = (y0 + yy) * IMG_W + (x0 + xx);
            atomicAdd(&acc[0 * IMG_H * IMG_W + pix], alpha * c0);
            atomicAdd(&acc[1 * IMG_H * IMG_W + pix], alpha * c1);
            atomicAdd(&acc[2 * IMG_H * IMG_W + pix], alpha * c2);
        }
    }
}

__global__ __launch_bounds__(256) void finalize_kernel(
    const float* __restrict__ acc,
    const float* __restrict__ scale,
    const float* __restrict__ shift,
    float* __restrict__ out)
{
    const int i = blockIdx.x * 256 + threadIdx.x;
    if (i < 3 * IMG_H * IMG_W) {
        out[i] = acc[i] * scale[0] + shift[0];
    }
}

extern "C" void kernel_launch(void* const* d_in, const int* in_sizes, int n_in,
                              void* d_out, int out_size, void* d_ws, size_t ws_size,
                              hipStream_t stream) {
    const float* xyz     = (const float*)d_in[0];
    const float* chol    = (const float*)d_in[1];
    const float* colors  = (const float*)d_in[2];
    const float* opacity = (const float*)d_in[3];
    const float* scale   = (const float*)d_in[4];
    const float* shift   = (const float*)d_in[5];
    float* out = (float*)d_out;

    const int N = in_sizes[3];  // opacity is (N,1)
    float* acc = (float*)d_ws;  // 3*256*256 fp32 = 786432 B

    hipMemsetAsync(acc, 0, 3 * IMG_H * IMG_W * sizeof(float), stream);
    splat_kernel<<<N, 64, 0, stream>>>(xyz, chol, colors, opacity, acc);
    const int total = 3 * IMG_H * IMG_W;
    finalize_kernel<<<(total + 255) / 256, 256, 0, stream>>>(acc, scale, shift, out);
}